// Round 6
// baseline (220.759 us; speedup 1.0000x reference)
//
#include <hip/hip_runtime.h>
#include <math.h>

// Problem constants
#define BB_ 8
#define C_ 512
#define C3_ 1536
#define HW_ 1024
#define NH_ 8
#define DH_ 64
#define HH_ 32
#define WW_ 32

typedef __attribute__((ext_vector_type(8))) short short8;
typedef __attribute__((ext_vector_type(4))) short short4v;
typedef __attribute__((ext_vector_type(8))) unsigned short ushort8;
typedef __attribute__((ext_vector_type(4))) unsigned short ushort4_t;
typedef __attribute__((ext_vector_type(4))) float f32x4;
typedef unsigned short ushort;

__device__ inline ushort f2bf(float f) {
  union { float f; unsigned u; } v;
  v.f = f;
  unsigned r = v.u + 0x7fffu + ((v.u >> 16) & 1u);
  return (ushort)(r >> 16);
}
__device__ inline float bf2f(ushort u) {
  union { unsigned u; float f; } v;
  v.u = ((unsigned)u) << 16;
  return v.f;
}

#define GLD16(gptr, lptr)                                                     \
  __builtin_amdgcn_global_load_lds(                                           \
      (const __attribute__((address_space(1))) unsigned int*)(gptr),          \
      (__attribute__((address_space(3))) unsigned int*)(lptr), 16, 0, 0)

// PV micro-op: D += Vt_frag(4 keys) x P_frag(4 keys), 16x16 output.
// Prefers true 16x16x16 bf16 MFMA; falls back to zero-padded 16x16x32.
__device__ inline f32x4 pv_mfma(const ushort* vp, short4v pf, f32x4 acc) {
#if __has_builtin(__builtin_amdgcn_mfma_f32_16x16x16_bf16)
  short4v vf = *(const short4v*)vp;
  return __builtin_amdgcn_mfma_f32_16x16x16_bf16(vf, pf, acc, 0, 0, 0);
#elif __has_builtin(__builtin_amdgcn_mfma_f32_16x16x16bf16_1k)
  short4v vf = *(const short4v*)vp;
  return __builtin_amdgcn_mfma_f32_16x16x16bf16_1k(vf, pf, acc, 0, 0, 0);
#else
  short4v v4 = *(const short4v*)vp;
  short8 vf = {v4[0], v4[1], v4[2], v4[3], 0, 0, 0, 0};
  short8 pf8 = {pf[0], pf[1], pf[2], pf[3], 0, 0, 0, 0};
  return __builtin_amdgcn_mfma_f32_16x16x32_bf16(vf, pf8, acc, 0, 0, 0);
#endif
}

// -------------------------------------------------------------------------
// K0: convert weights to bf16 (qkv_w | proj_w | pw_w concatenated)
__global__ void cvt_weights_kernel(const float* __restrict__ qkv_w,
                                   const float* __restrict__ proj_w,
                                   const float* __restrict__ pw_w,
                                   ushort* __restrict__ dst) {
  int i = blockIdx.x * 256 + threadIdx.x;
  if (i < 786432) dst[i] = f2bf(qkv_w[i]);
  else if (i < 1048576) dst[i] = f2bf(proj_w[i - 786432]);
  else dst[i] = f2bf(pw_w[i - 1048576]);
}

// -------------------------------------------------------------------------
// K1: tiled transpose. t[b,n,c] = bf16(x[b,c,n] + pos[n,c]); xT[b,n,c]=bf16(x)
__global__ __launch_bounds__(256) void add_pos_kernel(
    const float* __restrict__ x, const float* __restrict__ pos,
    ushort* __restrict__ t, ushort* __restrict__ xT) {
  __shared__ float tile[64][65];
  const int tid = threadIdx.x;
  const int n0 = blockIdx.x * 64, c0 = blockIdx.y * 64, b = blockIdx.z;
#pragma unroll
  for (int it = 0; it < 4; it++) {
    int c_l = (tid >> 4) + it * 16;
    int n_l4 = (tid & 15) * 4;
    float4 v = *(const float4*)&x[((size_t)(b * C_ + c0 + c_l)) * HW_ + n0 + n_l4];
    tile[c_l][n_l4 + 0] = v.x;
    tile[c_l][n_l4 + 1] = v.y;
    tile[c_l][n_l4 + 2] = v.z;
    tile[c_l][n_l4 + 3] = v.w;
  }
  __syncthreads();
#pragma unroll
  for (int it = 0; it < 4; it++) {
    int n_l = (tid >> 4) + it * 16;
    int c_l4 = (tid & 15) * 4;
    size_t token = (size_t)(b * HW_ + n0 + n_l);
    float4 pv = *(const float4*)&pos[(n0 + n_l) * C_ + c0 + c_l4];
    float xv0 = tile[c_l4 + 0][n_l], xv1 = tile[c_l4 + 1][n_l];
    float xv2 = tile[c_l4 + 2][n_l], xv3 = tile[c_l4 + 3][n_l];
    ushort4_t tb = {f2bf(xv0 + pv.x), f2bf(xv1 + pv.y), f2bf(xv2 + pv.z),
                    f2bf(xv3 + pv.w)};
    ushort4_t xb = {f2bf(xv0), f2bf(xv1), f2bf(xv2), f2bf(xv3)};
    *(ushort4_t*)&t[token * C_ + c0 + c_l4] = tb;
    *(ushort4_t*)&xT[token * C_ + c0 + c_l4] = xb;
  }
}

// -------------------------------------------------------------------------
// bf16 MFMA GEMM 128x128 (m97 structure), EPI0: bf16 token-major out.
__global__ __launch_bounds__(256) void gemm_128(
    const ushort* __restrict__ A, const ushort* __restrict__ Wm,
    ushort* __restrict__ out, int N, int K) {
  __shared__ alignas(16) ushort As[128 * 32];
  __shared__ alignas(16) ushort Bs[128 * 32];
  const int bn = blockIdx.x * 128, bm = blockIdx.y * 128;
  const int tid = threadIdx.x;
  const int w = tid >> 6, lane = tid & 63;
  const int wm = 64 * (w & 1), wn = 64 * (w >> 1);
  const int l15 = lane & 15, lq = lane >> 4;

  f32x4 acc[4][4];
#pragma unroll
  for (int i = 0; i < 4; i++)
#pragma unroll
    for (int j = 0; j < 4; j++) acc[i][j] = (f32x4){0.f, 0.f, 0.f, 0.f};

  const int srr = lane >> 2, sq1 = lane & 3;

  for (int k0 = 0; k0 < K; k0 += 32) {
    __syncthreads();
#pragma unroll
    for (int j = 0; j < 2; j++) {
      int r = 32 * w + 16 * j + srr;
      int q = (sq1 - (r >> 1)) & 3;
      GLD16(A + (size_t)(bm + r) * K + k0 + q * 8, &As[(32 * w + 16 * j) * 32]);
      GLD16(Wm + (size_t)(bn + r) * K + k0 + q * 8, &Bs[(32 * w + 16 * j) * 32]);
    }
    __syncthreads();
    short8 af[4], bf[4];
#pragma unroll
    for (int nt = 0; nt < 4; nt++) {
      int r = wm + nt * 16 + l15;
      af[nt] = *(const short8*)&As[r * 32 + (((lq + (r >> 1)) & 3) * 8)];
      int c = wn + nt * 16 + l15;
      bf[nt] = *(const short8*)&Bs[c * 32 + (((lq + (c >> 1)) & 3) * 8)];
    }
#pragma unroll
    for (int i = 0; i < 4; i++)
#pragma unroll
      for (int j = 0; j < 4; j++)
        acc[i][j] = __builtin_amdgcn_mfma_f32_16x16x32_bf16(af[i], bf[j],
                                                            acc[i][j], 0, 0, 0);
  }

#pragma unroll
  for (int i = 0; i < 4; i++) {
#pragma unroll
    for (int j = 0; j < 4; j++) {
      int c = bn + wn + j * 16 + l15;
#pragma unroll
      for (int r = 0; r < 4; r++) {
        int m = bm + wm + i * 16 + lq * 4 + r;
        out[(size_t)m * N + c] = f2bf(acc[i][j][r]);
      }
    }
  }
}

// -------------------------------------------------------------------------
// bf16 MFMA GEMM 128x64 tiles. EPI 1: f32 +bias. EPI 2: +resid, NCHW store.
template <int EPI>
__global__ __launch_bounds__(256) void gemm_n64(
    const ushort* __restrict__ A, const ushort* __restrict__ Wm,
    const float* __restrict__ bias, float* __restrict__ out,
    const float* __restrict__ resid, int N, int K) {
  __shared__ alignas(16) ushort As[128 * 32];
  __shared__ alignas(16) ushort Bs[64 * 32];
  const int bn = blockIdx.x * 64, bm = blockIdx.y * 128;
  const int tid = threadIdx.x;
  const int w = tid >> 6, lane = tid & 63;
  const int wm = 64 * (w & 1), wn = 32 * (w >> 1);
  const int l15 = lane & 15, lq = lane >> 4;

  f32x4 acc[4][2];
#pragma unroll
  for (int i = 0; i < 4; i++)
#pragma unroll
    for (int j = 0; j < 2; j++) acc[i][j] = (f32x4){0.f, 0.f, 0.f, 0.f};

  const int srr = lane >> 2, sq1 = lane & 3;

  for (int k0 = 0; k0 < K; k0 += 32) {
    __syncthreads();
#pragma unroll
    for (int j = 0; j < 2; j++) {
      int r = 32 * w + 16 * j + srr;
      int q = (sq1 - (r >> 1)) & 3;
      GLD16(A + (size_t)(bm + r) * K + k0 + q * 8, &As[(32 * w + 16 * j) * 32]);
    }
    {
      int r = 16 * w + srr;
      int q = (sq1 - (r >> 1)) & 3;
      GLD16(Wm + (size_t)(bn + r) * K + k0 + q * 8, &Bs[(16 * w) * 32]);
    }
    __syncthreads();
    short8 af[4], bf[2];
#pragma unroll
    for (int nt = 0; nt < 4; nt++) {
      int r = wm + nt * 16 + l15;
      af[nt] = *(const short8*)&As[r * 32 + (((lq + (r >> 1)) & 3) * 8)];
    }
#pragma unroll
    for (int j = 0; j < 2; j++) {
      int c = wn + j * 16 + l15;
      bf[j] = *(const short8*)&Bs[c * 32 + (((lq + (c >> 1)) & 3) * 8)];
    }
#pragma unroll
    for (int i = 0; i < 4; i++)
#pragma unroll
      for (int j = 0; j < 2; j++)
        acc[i][j] = __builtin_amdgcn_mfma_f32_16x16x32_bf16(af[i], bf[j],
                                                            acc[i][j], 0, 0, 0);
  }

#pragma unroll
  for (int i = 0; i < 4; i++) {
#pragma unroll
    for (int j = 0; j < 2; j++) {
      int c = bn + wn + j * 16 + l15;
      float bv = bias[c];
#pragma unroll
      for (int r = 0; r < 4; r++) {
        int m = bm + wm + i * 16 + lq * 4 + r;
        float v = acc[i][j][r] + bv;
        if (EPI == 1) {
          out[(size_t)m * N + c] = v;
        } else {
          int b = m >> 10, s = m & (HW_ - 1);
          out[((size_t)(b * C_ + c)) * HW_ + s] = v + resid[(size_t)m * C_ + c];
        }
      }
    }
  }
}

// -------------------------------------------------------------------------
// K2b: transpose V third of qkv into vt[bh][d][n] (bf16), tiled via LDS.
__global__ __launch_bounds__(256) void vt_kernel(const ushort* __restrict__ qkv,
                                                 ushort* __restrict__ vt) {
  __shared__ ushort tileT[64][72];
  const int bh = blockIdx.x >> 2, seg = blockIdx.x & 3;
  const int b = bh >> 3, h = bh & 7;
  const int tid = threadIdx.x;
  const ushort* src = qkv + (size_t)b * HW_ * C3_ + 2 * C_ + h * 64;
  for (int t = 0; t < 4; t++) {
    int n0 = seg * 256 + t * 64;
    __syncthreads();
#pragma unroll
    for (int it = 0; it < 2; it++) {
      int row = it * 32 + (tid >> 3);     // token within tile
      int c8 = (tid & 7) * 8;             // d chunk
      ushort8 v = *(const ushort8*)&src[(size_t)(n0 + row) * C3_ + c8];
#pragma unroll
      for (int j = 0; j < 8; j++) tileT[c8 + j][row] = v[j];
    }
    __syncthreads();
#pragma unroll
    for (int it = 0; it < 2; it++) {
      int d = it * 32 + (tid >> 3);
      int nch = (tid & 7) * 8;
      ushort8 o8 = *(const ushort8*)&tileT[d][nch];
      *(ushort8*)&vt[((size_t)(bh * 64 + d)) * HW_ + n0 + nch] = o8;
    }
  }
}

// -------------------------------------------------------------------------
// K3a: token-axis L2 partial sums (512 blocks: bh x 8 token-segments)
__global__ __launch_bounds__(256) void qk_norms_stage1(
    const ushort* __restrict__ qkv, float* __restrict__ partials) {
  __shared__ float smq[32][65], smk[32][65];
  const int blk = blockIdx.x;
  const int bh = blk >> 3, seg = blk & 7;
  const int b = bh >> 3, h = bh & 7;
  const int tid = threadIdx.x;
  const int trow = tid >> 3, chunk = tid & 7;
  float sq[8] = {}, sk[8] = {};
  const ushort* base = qkv + (size_t)b * HW_ * C3_ + h * 64 + chunk * 8;
#pragma unroll
  for (int i = 0; i < 4; i++) {
    int n = seg * 128 + i * 32 + trow;
    const ushort* p = base + (size_t)n * C3_;
    ushort8 q8 = *(const ushort8*)p;
    ushort8 k8 = *(const ushort8*)(p + C_);
#pragma unroll
    for (int j = 0; j < 8; j++) {
      float qv = bf2f(q8[j]), kv = bf2f(k8[j]);
      sq[j] += qv * qv;
      sk[j] += kv * kv;
    }
  }
#pragma unroll
  for (int j = 0; j < 8; j++) {
    smq[trow][chunk * 8 + j] = sq[j];
    smk[trow][chunk * 8 + j] = sk[j];
  }
  __syncthreads();
  if (tid < 64) {
    float s = 0.f;
    for (int i = 0; i < 32; i++) s += smq[i][tid];
    partials[((size_t)(bh * 8 + seg) * 2 + 0) * 64 + tid] = s;
  } else if (tid < 128) {
    int d = tid - 64;
    float s = 0.f;
    for (int i = 0; i < 32; i++) s += smk[i][d];
    partials[((size_t)(bh * 8 + seg) * 2 + 1) * 64 + d] = s;
  }
}

// K3b: finalize norms
__global__ void qk_norms_stage2(const float* __restrict__ partials,
                                float* __restrict__ invq,
                                float* __restrict__ invk) {
  const int bh = blockIdx.x;
  const int tid = threadIdx.x;
  const int which = tid >> 6, d = tid & 63;
  float s = 0.f;
#pragma unroll
  for (int seg = 0; seg < 8; seg++)
    s += partials[((size_t)(bh * 8 + seg) * 2 + which) * 64 + d];
  float r = 1.0f / fmaxf(sqrtf(s), 1e-12f);
  if (which == 0) invq[bh * 64 + d] = r;
  else invk[bh * 64 + d] = r;
}

// -------------------------------------------------------------------------
// K4: MFMA flash attention v4. Computes S^T = K·Q^T so the P matrix feeds
// the PV MFMA directly from registers (C-layout == x16 A/B-frag layout).
// K and V^T both staged via global_load_lds with XOR chunk swizzles; no
// LDS round trip for P; fixed-max softmax (scores bounded ~0.07).
__global__ __launch_bounds__(512) void attn_mfma_kernel(
    const ushort* __restrict__ qkv, const ushort* __restrict__ vt,
    const float* __restrict__ invq, const float* __restrict__ invk,
    const float* __restrict__ temp, ushort* __restrict__ o) {
  __shared__ alignas(16) ushort Ks[64 * 64];   // [key][d], chunk-swizzled
  __shared__ alignas(16) ushort Vts[64 * 64];  // [d][key], chunk-swizzled

  const int tid = threadIdx.x;
  const int w = tid >> 6, lane = tid & 63;
  const int quad = lane >> 4, lcol = lane & 15;
  const int bh = blockIdx.x >> 3;
  const int qt = blockIdx.x & 7;
  const int b = bh >> 3, h = bh & 7;
  const int q0 = qt * 128;

  // Q fragment (B-operand of S^T = K·Q^T), scales folded in.
  short8 qf[2];
  {
    const int m = q0 + w * 16 + lcol;
    const ushort* qrow = qkv + ((size_t)(b * HW_ + m)) * C3_ + h * 64;
    const float tmp = temp[h];
#pragma unroll
    for (int kc = 0; kc < 2; kc++) {
      union { short8 v; ushort u[8]; } pk;
#pragma unroll
      for (int j = 0; j < 8; j++) {
        int d = kc * 32 + quad * 8 + j;
        float s = invq[bh * 64 + d] * invk[bh * 64 + d] * tmp;
        pk.u[j] = f2bf(bf2f(qrow[d]) * s);
      }
      qf[kc] = pk.v;
    }
  }

  f32x4 ot[4];  // O^T: per dt, lane holds d=dt*16+quad*4+r, query=lcol
#pragma unroll
  for (int dt = 0; dt < 4; dt++) ot[dt] = (f32x4){0.f, 0.f, 0.f, 0.f};
  float lsum = 0.f;

  const ushort* kg = qkv + (size_t)b * HW_ * C3_ + C_ + h * 64;
  const ushort* vg = vt + (size_t)(bh * 64) * HW_;

  // staging coords: 512 threads cover 64 rows x 8 chunks (of 8 bf16)
  const int srow = tid >> 3;
  const int sc = tid & 7;
  const int scg = sc ^ (srow & 7);  // global chunk fetched into slot sc

  for (int kt = 0; kt < 16; kt++) {
    __syncthreads();
    GLD16(kg + (size_t)(kt * 64 + srow) * C3_ + scg * 8, &Ks[w * 512]);
    GLD16(vg + (size_t)srow * HW_ + kt * 64 + scg * 8, &Vts[w * 512]);
    __syncthreads();

    // S^T = K·Q^T: sfr[nt] holds keys nt*16+quad*4+r, query lcol
    f32x4 sfr[4];
#pragma unroll
    for (int nt = 0; nt < 4; nt++) sfr[nt] = (f32x4){0.f, 0.f, 0.f, 0.f};
#pragma unroll
    for (int kc = 0; kc < 2; kc++) {
#pragma unroll
      for (int nt = 0; nt < 4; nt++) {
        int row = nt * 16 + lcol;
        short8 kf = *(const short8*)
            &Ks[row * 64 + (((kc * 4 + quad) ^ (row & 7)) * 8)];
        sfr[nt] =
            __builtin_amdgcn_mfma_f32_16x16x32_bf16(kf, qf[kc], sfr[nt], 0, 0, 0);
      }
    }

    // exp (fixed max) + per-lane partial sum + pack P
    ushort pk[4][4];
#pragma unroll
    for (int nt = 0; nt < 4; nt++) {
#pragma unroll
      for (int r = 0; r < 4; r++) {
        float e = __expf(sfr[nt][r]);
        lsum += e;
        pk[nt][r] = f2bf(e);
      }
    }

    // O^T += V^T · P^T  (x16 MFMAs, P from registers)
#pragma unroll
    for (int nt = 0; nt < 4; nt++) {
      short4v pf = {(short)pk[nt][0], (short)pk[nt][1], (short)pk[nt][2],
                    (short)pk[nt][3]};
      int key = nt * 16 + quad * 4;
#pragma unroll
      for (int dt = 0; dt < 4; dt++) {
        int d = dt * 16 + lcol;
        const ushort* vp =
            &Vts[d * 64 + (((key >> 3) ^ (d & 7)) * 8) + (key & 7)];
        ot[dt] = pv_mfma(vp, pf, ot[dt]);
      }
    }
  }

  // total softmax denominator for query lcol: sum across quads
  lsum += __shfl_xor(lsum, 16);
  lsum += __shfl_xor(lsum, 32);
  const float inv = 1.0f / lsum;

  const int m = q0 + w * 16 + lcol;
  ushort* orow = o + ((size_t)(b * HW_ + m)) * C_ + h * 64;
#pragma unroll
  for (int dt = 0; dt < 4; dt++) {
    ushort4_t pkb = {f2bf(ot[dt][0] * inv), f2bf(ot[dt][1] * inv),
                     f2bf(ot[dt][2] * inv), f2bf(ot[dt][3] * inv)};
    *(ushort4_t*)&orow[dt * 16 + quad * 4] = pkb;
  }
}

// -------------------------------------------------------------------------
// K6: LayerNorm + residual(xT bf16). po -> f32 y in place; bf16 copy to ybf.
__global__ void ln_residual_kernel(float* __restrict__ po, const ushort* xT,
                                   const float* __restrict__ g,
                                   const float* __restrict__ bb, ushort* ybf) {
  int token = blockIdx.x;
  int t = threadIdx.x;
  float* row = po + (size_t)token * C_;
  float v0 = row[t], v1 = row[t + 256];
  float s = v0 + v1;
#pragma unroll
  for (int off = 32; off; off >>= 1) s += __shfl_xor(s, off);
  __shared__ float wr[4];
  if ((t & 63) == 0) wr[t >> 6] = s;
  __syncthreads();
  float mu = (wr[0] + wr[1] + wr[2] + wr[3]) * (1.0f / C_);
  float d0 = v0 - mu, d1 = v1 - mu;
  float vs = d0 * d0 + d1 * d1;
#pragma unroll
  for (int off = 32; off; off >>= 1) vs += __shfl_xor(vs, off);
  __syncthreads();
  if ((t & 63) == 0) wr[t >> 6] = vs;
  __syncthreads();
  float var = (wr[0] + wr[1] + wr[2] + wr[3]) * (1.0f / C_);
  float rstd = rsqrtf(var + 1e-5f);
  float r0 = bf2f(xT[(size_t)token * C_ + t]);
  float r1 = bf2f(xT[(size_t)token * C_ + t + 256]);
  float o0 = d0 * rstd * g[t] + bb[t] + r0;
  float o1 = d1 * rstd * g[t + 256] + bb[t + 256] + r1;
  row[t] = o0;
  row[t + 256] = o1;
  ybf[(size_t)token * C_ + t] = f2bf(o0);
  ybf[(size_t)token * C_ + t + 256] = f2bf(o1);
}

// -------------------------------------------------------------------------
// K7: depthwise 3x3 SAME on bf16 y (token-major) -> bf16 out (+dw bias)
__global__ __launch_bounds__(256) void dwconv_kernel(
    const ushort* __restrict__ y, const float* __restrict__ w,
    const float* __restrict__ bias, ushort* __restrict__ out) {
  const int cg = threadIdx.x & 63, tg = threadIdx.x >> 6;
  const int c0 = cg * 8;
  float wreg[9][8], breg[8];
#pragma unroll
  for (int j = 0; j < 8; j++) {
    breg[j] = bias[c0 + j];
#pragma unroll
    for (int kk = 0; kk < 9; kk++) wreg[kk][j] = w[(c0 + j) * 9 + kk];
  }
  for (int i = 0; i < 4; i++) {
    int token = blockIdx.x * 16 + tg * 4 + i;
    int b = token >> 10, s = token & (HW_ - 1);
    int hh = s >> 5, ww = s & 31;
    float acc[8];
#pragma unroll
    for (int j = 0; j < 8; j++) acc[j] = breg[j];
#pragma unroll
    for (int ky = 0; ky < 3; ky++) {
      int yy = hh + ky - 1;
      if (yy < 0 || yy >= HH_) continue;
#pragma unroll
      for (int kx = 0; kx < 3; kx++) {
        int xx = ww + kx - 1;
        if (xx < 0 || xx >= WW_) continue;
        ushort8 v8 = *(const ushort8*)
            &y[((size_t)(b * HW_ + yy * 32 + xx)) * C_ + c0];
        const float* wk = wreg[ky * 3 + kx];
#pragma unroll
        for (int j = 0; j < 8; j++) acc[j] += wk[j] * bf2f(v8[j]);
      }
    }
    ushort8 pk;
#pragma unroll
    for (int j = 0; j < 8; j++) pk[j] = f2bf(acc[j]);
    *(ushort8*)&out[(size_t)token * C_ + c0] = pk;
  }
}

// -------------------------------------------------------------------------
extern "C" void kernel_launch(void* const* d_in, const int* in_sizes, int n_in,
                              void* d_out, int out_size, void* d_ws,
                              size_t ws_size, hipStream_t stream) {
  const float* x = (const float*)d_in[0];
  const float* qkv_w = (const float*)d_in[1];
  const float* proj_w = (const float*)d_in[2];
  const float* proj_b = (const float*)d_in[3];
  const float* temperature = (const float*)d_in[4];
  const float* ln_g = (const float*)d_in[5];
  const float* ln_b = (const float*)d_in[6];
  const float* pos = (const float*)d_in[7];
  const float* dw_w = (const float*)d_in[8];
  const float* dw_b = (const float*)d_in[9];
  const float* pw_w = (const float*)d_in[10];
  const float* pw_b = (const float*)d_in[11];
  float* out = (float*)d_out;

  float* ws = (float*)d_ws;
  // [0,24MB)    qkv_bf (bf16)
  // [24,32MB)   t_bf -> attn_out_bf -> dw_out_bf (bf16)
  // [32,48MB)   proj_out f32 -> y f32 (LN in-place, pw residual)
  // [48,56MB)   xT bf16 -> y_bf (ln overwrites in place)
  // [56,58.6MB) weights bf16
  // [60MB,...)  invq/invk/partials
  // [64,72MB)   vt (V transposed, bf16)
  ushort* qkv_bf = (ushort*)ws;
  ushort* t_bf = (ushort*)(ws + (size_t)6 * 1024 * 1024);
  float* proj_out = ws + (size_t)8 * 1024 * 1024;
  ushort* xT_bf = (ushort*)(ws + (size_t)12 * 1024 * 1024);
  ushort* wts = (ushort*)(ws + (size_t)14 * 1024 * 1024);
  ushort* qkvw_bf = wts;
  ushort* projw_bf = wts + 786432;
  ushort* pww_bf = wts + 1048576;
  float* invq = ws + (size_t)15 * 1024 * 1024;
  float* invk = invq + 512;
  float* partials = invk + 512;  // 512*128 floats
  ushort* vtb = (ushort*)(ws + (size_t)16 * 1024 * 1024);

  const int M = BB_ * HW_;  // 8192 tokens

  // 0) weights -> bf16
  cvt_weights_kernel<<<1310720 / 256, 256, 0, stream>>>(qkv_w, proj_w, pw_w,
                                                        wts);
  // 1) t = bf16(x^T + pos), xT = bf16(x^T)
  add_pos_kernel<<<dim3(16, 8, 8), 256, 0, stream>>>(x, pos, t_bf, xT_bf);
  // 2) qkv GEMM (bf16 out)
  gemm_128<<<dim3(C3_ / 128, M / 128), 256, 0, stream>>>(t_bf, qkvw_bf,
                                                         qkv_bf, C3_, C_);
  // 2b) V transpose -> vt[bh][d][n]
  vt_kernel<<<256, 256, 0, stream>>>(qkv_bf, vtb);
  // 3) q/k token-axis norms (two-stage)
  qk_norms_stage1<<<512, 256, 0, stream>>>(qkv_bf, partials);
  qk_norms_stage2<<<64, 128, 0, stream>>>(partials, invq, invk);
  // 4) flash attention -> attn_out (bf16, reuses t region)
  attn_mfma_kernel<<<BB_ * NH_ * (HW_ / 128), 512, 0, stream>>>(
      qkv_bf, vtb, invq, invk, temperature, t_bf);
  // 5) proj GEMM (+bias, f32 out)
  gemm_n64<1><<<dim3(C_ / 64, M / 128), 256, 0, stream>>>(
      t_bf, projw_bf, proj_b, proj_out, nullptr, C_, C_);
  // 6) LayerNorm + residual(xT): proj_out -> y f32 (in place) + y_bf
  ln_residual_kernel<<<M, 256, 0, stream>>>(proj_out, xT_bf, ln_g, ln_b,
                                            xT_bf);
  // 7) depthwise 3x3 on bf16 y -> dw_out (bf16, reuses t region)
  dwconv_kernel<<<M / 16, 256, 0, stream>>>(xT_bf, dw_w, dw_b, t_bf);
  // 8) pointwise GEMM + pw_b + residual(y f32), NCHW -> out
  gemm_n64<2><<<dim3(C_ / 64, M / 128), 256, 0, stream>>>(
      t_bf, pww_bf, pw_b, out, proj_out, C_, C_);
}

// Round 7
// 213.783 us; speedup vs baseline: 1.0326x; 1.0326x over previous
//
#include <hip/hip_runtime.h>
#include <math.h>

// Problem constants
#define BB_ 8
#define C_ 512
#define C3_ 1536
#define HW_ 1024
#define NH_ 8
#define DH_ 64
#define HH_ 32
#define WW_ 32

typedef __attribute__((ext_vector_type(8))) short short8;
typedef __attribute__((ext_vector_type(4))) short short4v;
typedef __attribute__((ext_vector_type(8))) unsigned short ushort8;
typedef __attribute__((ext_vector_type(4))) unsigned short ushort4_t;
typedef __attribute__((ext_vector_type(4))) float f32x4;
typedef unsigned short ushort;

__device__ inline ushort f2bf(float f) {
  union { float f; unsigned u; } v;
  v.f = f;
  unsigned r = v.u + 0x7fffu + ((v.u >> 16) & 1u);
  return (ushort)(r >> 16);
}
__device__ inline float bf2f(ushort u) {
  union { unsigned u; float f; } v;
  v.u = ((unsigned)u) << 16;
  return v.f;
}

#define GLD16(gptr, lptr)                                                     \
  __builtin_amdgcn_global_load_lds(                                           \
      (const __attribute__((address_space(1))) unsigned int*)(gptr),          \
      (__attribute__((address_space(3))) unsigned int*)(lptr), 16, 0, 0)

// PV micro-op: D += Vt_frag(4 keys) x P_frag(4 keys), 16x16 output.
__device__ inline f32x4 pv_mfma(const ushort* vp, short4v pf, f32x4 acc) {
#if __has_builtin(__builtin_amdgcn_mfma_f32_16x16x16_bf16)
  short4v vf = *(const short4v*)vp;
  return __builtin_amdgcn_mfma_f32_16x16x16_bf16(vf, pf, acc, 0, 0, 0);
#elif __has_builtin(__builtin_amdgcn_mfma_f32_16x16x16bf16_1k)
  short4v vf = *(const short4v*)vp;
  return __builtin_amdgcn_mfma_f32_16x16x16bf16_1k(vf, pf, acc, 0, 0, 0);
#else
  short4v v4 = *(const short4v*)vp;
  short8 vf = {v4[0], v4[1], v4[2], v4[3], 0, 0, 0, 0};
  short8 pf8 = {pf[0], pf[1], pf[2], pf[3], 0, 0, 0, 0};
  return __builtin_amdgcn_mfma_f32_16x16x32_bf16(vf, pf8, acc, 0, 0, 0);
#endif
}

// -------------------------------------------------------------------------
// K1 (prep): fused weight-cvt + x transpose(+pos) + qsum/ksum zeroing.
// bid < 1024        : add_pos tile (64x64 transpose)
// 1024 <= bid < 6144: weights -> bf16
// 6144 <= bid < 6176: zero qsum/ksum (8192 floats)
__global__ __launch_bounds__(256) void prep_kernel(
    const float* __restrict__ x, const float* __restrict__ pos,
    const float* __restrict__ qkv_w, const float* __restrict__ proj_w,
    const float* __restrict__ pw_w, ushort* __restrict__ t,
    ushort* __restrict__ xT, ushort* __restrict__ wts,
    float* __restrict__ sums) {
  const int bid = blockIdx.x;
  const int tid = threadIdx.x;
  if (bid >= 6144) {
    sums[(bid - 6144) * 256 + tid] = 0.f;
    return;
  }
  if (bid >= 1024) {
    int i = (bid - 1024) * 256 + tid;
    if (i < 786432) wts[i] = f2bf(qkv_w[i]);
    else if (i < 1048576) wts[i] = f2bf(proj_w[i - 786432]);
    else wts[i] = f2bf(pw_w[i - 1048576]);
    return;
  }
  __shared__ float tile[64][65];
  const int n0 = (bid & 15) * 64, c0 = ((bid >> 4) & 7) * 64, b = bid >> 7;
#pragma unroll
  for (int it = 0; it < 4; it++) {
    int c_l = (tid >> 4) + it * 16;
    int n_l4 = (tid & 15) * 4;
    float4 v = *(const float4*)&x[((size_t)(b * C_ + c0 + c_l)) * HW_ + n0 + n_l4];
    tile[c_l][n_l4 + 0] = v.x;
    tile[c_l][n_l4 + 1] = v.y;
    tile[c_l][n_l4 + 2] = v.z;
    tile[c_l][n_l4 + 3] = v.w;
  }
  __syncthreads();
#pragma unroll
  for (int it = 0; it < 4; it++) {
    int n_l = (tid >> 4) + it * 16;
    int c_l4 = (tid & 15) * 4;
    size_t token = (size_t)(b * HW_ + n0 + n_l);
    float4 pv = *(const float4*)&pos[(n0 + n_l) * C_ + c0 + c_l4];
    float xv0 = tile[c_l4 + 0][n_l], xv1 = tile[c_l4 + 1][n_l];
    float xv2 = tile[c_l4 + 2][n_l], xv3 = tile[c_l4 + 3][n_l];
    ushort4_t tb = {f2bf(xv0 + pv.x), f2bf(xv1 + pv.y), f2bf(xv2 + pv.z),
                    f2bf(xv3 + pv.w)};
    ushort4_t xb = {f2bf(xv0), f2bf(xv1), f2bf(xv2), f2bf(xv3)};
    *(ushort4_t*)&t[token * C_ + c0 + c_l4] = tb;
    *(ushort4_t*)&xT[token * C_ + c0 + c_l4] = xb;
  }
}

// -------------------------------------------------------------------------
// K2: qkv GEMM (m97 structure, 128x128). Epilogue:
//  - q/k columns (c<1024): bf16 store + fused token-axis sum-of-squares
//    accumulation into qsum/ksum (device atomics, f32 pre-round values)
//  - v columns (c>=1024): transposed bf16 store into vt[bh*64+d][n]
__global__ __launch_bounds__(256) void gemm_qkv(
    const ushort* __restrict__ A, const ushort* __restrict__ Wm,
    ushort* __restrict__ out, ushort* __restrict__ vt,
    float* __restrict__ qsum, float* __restrict__ ksum) {
  const int N = C3_, K = C_;
  __shared__ alignas(16) ushort As[128 * 32];
  __shared__ alignas(16) ushort Bs[128 * 32];
  const int bn = blockIdx.x * 128, bm = blockIdx.y * 128;
  const int tid = threadIdx.x;
  const int w = tid >> 6, lane = tid & 63;
  const int wm = 64 * (w & 1), wn = 64 * (w >> 1);
  const int l15 = lane & 15, lq = lane >> 4;

  f32x4 acc[4][4];
#pragma unroll
  for (int i = 0; i < 4; i++)
#pragma unroll
    for (int j = 0; j < 4; j++) acc[i][j] = (f32x4){0.f, 0.f, 0.f, 0.f};

  const int srr = lane >> 2, sq1 = lane & 3;

  for (int k0 = 0; k0 < K; k0 += 32) {
    __syncthreads();
#pragma unroll
    for (int j = 0; j < 2; j++) {
      int r = 32 * w + 16 * j + srr;
      int q = (sq1 - (r >> 1)) & 3;
      GLD16(A + (size_t)(bm + r) * K + k0 + q * 8, &As[(32 * w + 16 * j) * 32]);
      GLD16(Wm + (size_t)(bn + r) * K + k0 + q * 8, &Bs[(32 * w + 16 * j) * 32]);
    }
    __syncthreads();
    short8 af[4], bf[4];
#pragma unroll
    for (int nt = 0; nt < 4; nt++) {
      int r = wm + nt * 16 + l15;
      af[nt] = *(const short8*)&As[r * 32 + (((lq + (r >> 1)) & 3) * 8)];
      int c = wn + nt * 16 + l15;
      bf[nt] = *(const short8*)&Bs[c * 32 + (((lq + (c >> 1)) & 3) * 8)];
    }
#pragma unroll
    for (int i = 0; i < 4; i++)
#pragma unroll
      for (int j = 0; j < 4; j++)
        acc[i][j] = __builtin_amdgcn_mfma_f32_16x16x32_bf16(af[i], bf[j],
                                                            acc[i][j], 0, 0, 0);
  }

  const int b = bm >> 10;
  if (bn < 1024) {
    // q/k: normal store + norm accumulation
#pragma unroll
    for (int j = 0; j < 4; j++) {
      int c = bn + wn + j * 16 + l15;
      float ss = 0.f;
#pragma unroll
      for (int i = 0; i < 4; i++) {
#pragma unroll
        for (int r = 0; r < 4; r++) {
          int m = bm + wm + i * 16 + lq * 4 + r;
          float v = acc[i][j][r];
          ss += v * v;
          out[(size_t)m * N + c] = f2bf(v);
        }
      }
      ss += __shfl_xor(ss, 16);
      ss += __shfl_xor(ss, 32);
      if (lq == 0) {
        if (c < 512) atomicAdd(&qsum[b * 512 + c], ss);
        else atomicAdd(&ksum[b * 512 + c - 512], ss);
      }
    }
  } else {
    // V: transposed store vt[(bh*64+d)][n]
#pragma unroll
    for (int j = 0; j < 4; j++) {
      int c = bn + wn + j * 16 + l15;
      int hd = c - 1024;
      ushort* vrow = vt + ((size_t)(b * 512 + hd)) * HW_;
#pragma unroll
      for (int i = 0; i < 4; i++) {
        int n0 = (bm & 1023) + wm + i * 16 + lq * 4;
        ushort4_t pv = {f2bf(acc[i][j][0]), f2bf(acc[i][j][1]),
                        f2bf(acc[i][j][2]), f2bf(acc[i][j][3])};
        *(ushort4_t*)&vrow[n0] = pv;
      }
    }
  }
}

// -------------------------------------------------------------------------
// bf16 MFMA GEMM 128x64 tiles. EPI 1: bf16 +bias token-major.
// EPI 2: f32 +bias +resid(bf16), NCHW store.
template <int EPI>
__global__ __launch_bounds__(256) void gemm_n64(
    const ushort* __restrict__ A, const ushort* __restrict__ Wm,
    const float* __restrict__ bias, void* __restrict__ outv,
    const ushort* __restrict__ resid, int N, int K) {
  __shared__ alignas(16) ushort As[128 * 32];
  __shared__ alignas(16) ushort Bs[64 * 32];
  const int bn = blockIdx.x * 64, bm = blockIdx.y * 128;
  const int tid = threadIdx.x;
  const int w = tid >> 6, lane = tid & 63;
  const int wm = 64 * (w & 1), wn = 32 * (w >> 1);
  const int l15 = lane & 15, lq = lane >> 4;

  f32x4 acc[4][2];
#pragma unroll
  for (int i = 0; i < 4; i++)
#pragma unroll
    for (int j = 0; j < 2; j++) acc[i][j] = (f32x4){0.f, 0.f, 0.f, 0.f};

  const int srr = lane >> 2, sq1 = lane & 3;

  for (int k0 = 0; k0 < K; k0 += 32) {
    __syncthreads();
#pragma unroll
    for (int j = 0; j < 2; j++) {
      int r = 32 * w + 16 * j + srr;
      int q = (sq1 - (r >> 1)) & 3;
      GLD16(A + (size_t)(bm + r) * K + k0 + q * 8, &As[(32 * w + 16 * j) * 32]);
    }
    {
      int r = 16 * w + srr;
      int q = (sq1 - (r >> 1)) & 3;
      GLD16(Wm + (size_t)(bn + r) * K + k0 + q * 8, &Bs[(16 * w) * 32]);
    }
    __syncthreads();
    short8 af[4], bf[2];
#pragma unroll
    for (int nt = 0; nt < 4; nt++) {
      int r = wm + nt * 16 + l15;
      af[nt] = *(const short8*)&As[r * 32 + (((lq + (r >> 1)) & 3) * 8)];
    }
#pragma unroll
    for (int j = 0; j < 2; j++) {
      int c = wn + j * 16 + l15;
      bf[j] = *(const short8*)&Bs[c * 32 + (((lq + (c >> 1)) & 3) * 8)];
    }
#pragma unroll
    for (int i = 0; i < 4; i++)
#pragma unroll
      for (int j = 0; j < 2; j++)
        acc[i][j] = __builtin_amdgcn_mfma_f32_16x16x32_bf16(af[i], bf[j],
                                                            acc[i][j], 0, 0, 0);
  }

#pragma unroll
  for (int i = 0; i < 4; i++) {
#pragma unroll
    for (int j = 0; j < 2; j++) {
      int c = bn + wn + j * 16 + l15;
      float bv = bias[c];
#pragma unroll
      for (int r = 0; r < 4; r++) {
        int m = bm + wm + i * 16 + lq * 4 + r;
        float v = acc[i][j][r] + bv;
        if (EPI == 1) {
          ((ushort*)outv)[(size_t)m * N + c] = f2bf(v);
        } else {
          int b = m >> 10, s = m & (HW_ - 1);
          ((float*)outv)[((size_t)(b * C_ + c)) * HW_ + s] =
              v + bf2f(resid[(size_t)m * C_ + c]);
        }
      }
    }
  }
}

// -------------------------------------------------------------------------
// K3: MFMA flash attention. 4 waves = 64 queries/block (grid 1024 -> 4
// blocks/CU, decoupled barrier domains). Per-block prologue derives the
// folded scale from qsum/ksum. S^T = K·Q^T; P feeds PV from registers.
__global__ __launch_bounds__(256) void attn_mfma_kernel(
    const ushort* __restrict__ qkv, const ushort* __restrict__ vt,
    const float* __restrict__ qsum, const float* __restrict__ ksum,
    const float* __restrict__ temp, ushort* __restrict__ o) {
  __shared__ alignas(16) ushort Ks[64 * 64];   // [key][d], chunk-swizzled
  __shared__ alignas(16) ushort Vts[64 * 64];  // [d][key], chunk-swizzled
  __shared__ float sc_lds[64];

  const int tid = threadIdx.x;
  const int w = tid >> 6, lane = tid & 63;
  const int quad = lane >> 4, lcol = lane & 15;
  const int bh = blockIdx.x >> 4;
  const int qt = blockIdx.x & 15;
  const int b = bh >> 3, h = bh & 7;
  const int q0 = qt * 64;

  if (tid < 64) {
    float qs = qsum[b * 512 + h * 64 + tid];
    float ks = ksum[b * 512 + h * 64 + tid];
    float iq = 1.0f / fmaxf(sqrtf(qs), 1e-12f);
    float ik = 1.0f / fmaxf(sqrtf(ks), 1e-12f);
    sc_lds[tid] = iq * ik * temp[h];
  }
  __syncthreads();

  // Q fragment (B-operand of S^T = K·Q^T), scales folded in.
  short8 qf[2];
  {
    const int m = q0 + w * 16 + lcol;
    const ushort* qrow = qkv + ((size_t)(b * HW_ + m)) * C3_ + h * 64;
#pragma unroll
    for (int kc = 0; kc < 2; kc++) {
      union { short8 v; ushort u[8]; } pk;
#pragma unroll
      for (int j = 0; j < 8; j++) {
        int d = kc * 32 + quad * 8 + j;
        pk.u[j] = f2bf(bf2f(qrow[d]) * sc_lds[d]);
      }
      qf[kc] = pk.v;
    }
  }

  f32x4 ot[4];  // O^T: per dt, lane holds d=dt*16+quad*4+r, query=lcol
#pragma unroll
  for (int dt = 0; dt < 4; dt++) ot[dt] = (f32x4){0.f, 0.f, 0.f, 0.f};
  float lsum = 0.f;

  const ushort* kg = qkv + (size_t)b * HW_ * C3_ + C_ + h * 64;
  const ushort* vg = vt + (size_t)(bh * 64) * HW_;

  // staging: 256 threads x 2 iters cover 64 rows x 8 chunks (of 8 bf16)
  const int srow0 = tid >> 3;          // 0..31
  const int sc = tid & 7;

  for (int kt = 0; kt < 16; kt++) {
    __syncthreads();
#pragma unroll
    for (int it = 0; it < 2; it++) {
      int row = srow0 + it * 32;
      int scg = sc ^ (row & 7);
      GLD16(kg + (size_t)(kt * 64 + row) * C3_ + scg * 8,
            &Ks[w * 512 + it * 2048]);
      GLD16(vg + (size_t)row * HW_ + kt * 64 + scg * 8,
            &Vts[w * 512 + it * 2048]);
    }
    __syncthreads();

    // S^T = K·Q^T: sfr[nt] holds keys nt*16+quad*4+r, query lcol
    f32x4 sfr[4];
#pragma unroll
    for (int nt = 0; nt < 4; nt++) sfr[nt] = (f32x4){0.f, 0.f, 0.f, 0.f};
#pragma unroll
    for (int kc = 0; kc < 2; kc++) {
#pragma unroll
      for (int nt = 0; nt < 4; nt++) {
        int row = nt * 16 + lcol;
        short8 kf = *(const short8*)
            &Ks[row * 64 + (((kc * 4 + quad) ^ (row & 7)) * 8)];
        sfr[nt] =
            __builtin_amdgcn_mfma_f32_16x16x32_bf16(kf, qf[kc], sfr[nt], 0, 0, 0);
      }
    }

    // exp (fixed max: scores bounded ~0.07) + per-lane sum + pack P
    ushort pk[4][4];
#pragma unroll
    for (int nt = 0; nt < 4; nt++) {
#pragma unroll
      for (int r = 0; r < 4; r++) {
        float e = __expf(sfr[nt][r]);
        lsum += e;
        pk[nt][r] = f2bf(e);
      }
    }

    // O^T += V^T · P^T  (x16 MFMAs, P from registers)
#pragma unroll
    for (int nt = 0; nt < 4; nt++) {
      short4v pf = {(short)pk[nt][0], (short)pk[nt][1], (short)pk[nt][2],
                    (short)pk[nt][3]};
      int key = nt * 16 + quad * 4;
#pragma unroll
      for (int dt = 0; dt < 4; dt++) {
        int d = dt * 16 + lcol;
        const ushort* vp =
            &Vts[d * 64 + (((key >> 3) ^ (d & 7)) * 8) + (key & 7)];
        ot[dt] = pv_mfma(vp, pf, ot[dt]);
      }
    }
  }

  lsum += __shfl_xor(lsum, 16);
  lsum += __shfl_xor(lsum, 32);
  const float inv = 1.0f / lsum;

  const int m = q0 + w * 16 + lcol;
  ushort* orow = o + ((size_t)(b * HW_ + m)) * C_ + h * 64;
#pragma unroll
  for (int dt = 0; dt < 4; dt++) {
    ushort4_t pkb = {f2bf(ot[dt][0] * inv), f2bf(ot[dt][1] * inv),
                     f2bf(ot[dt][2] * inv), f2bf(ot[dt][3] * inv)};
    *(ushort4_t*)&orow[dt * 16 + quad * 4] = pkb;
  }
}

// -------------------------------------------------------------------------
// K5: LayerNorm (bf16 in) + residual(xT bf16) -> bf16 y (in place over xT).
__global__ void ln_residual_kernel(const ushort* __restrict__ po,
                                   const ushort* xT,
                                   const float* __restrict__ g,
                                   const float* __restrict__ bb, ushort* ybf) {
  int token = blockIdx.x;
  int t = threadIdx.x;
  const unsigned pv = *(const unsigned*)&po[(size_t)token * C_ + 2 * t];
  float v0 = bf2f((ushort)(pv & 0xffff)), v1 = bf2f((ushort)(pv >> 16));
  float s = v0 + v1;
#pragma unroll
  for (int off = 32; off; off >>= 1) s += __shfl_xor(s, off);
  __shared__ float wr[4];
  if ((t & 63) == 0) wr[t >> 6] = s;
  __syncthreads();
  float mu = (wr[0] + wr[1] + wr[2] + wr[3]) * (1.0f / C_);
  float d0 = v0 - mu, d1 = v1 - mu;
  float vs = d0 * d0 + d1 * d1;
#pragma unroll
  for (int off = 32; off; off >>= 1) vs += __shfl_xor(vs, off);
  __syncthreads();
  if ((t & 63) == 0) wr[t >> 6] = vs;
  __syncthreads();
  float var = (wr[0] + wr[1] + wr[2] + wr[3]) * (1.0f / C_);
  float rstd = rsqrtf(var + 1e-5f);
  const unsigned rv = *(const unsigned*)&xT[(size_t)token * C_ + 2 * t];
  float o0 = d0 * rstd * g[2 * t] + bb[2 * t] + bf2f((ushort)(rv & 0xffff));
  float o1 = d1 * rstd * g[2 * t + 1] + bb[2 * t + 1] + bf2f((ushort)(rv >> 16));
  unsigned ov = (unsigned)f2bf(o0) | ((unsigned)f2bf(o1) << 16);
  *(unsigned*)&ybf[(size_t)token * C_ + 2 * t] = ov;
}

// -------------------------------------------------------------------------
// K6: depthwise 3x3 SAME on bf16 y (token-major) -> bf16 out (+dw bias)
__global__ __launch_bounds__(256) void dwconv_kernel(
    const ushort* __restrict__ y, const float* __restrict__ w,
    const float* __restrict__ bias, ushort* __restrict__ out) {
  const int cg = threadIdx.x & 63, tg = threadIdx.x >> 6;
  const int c0 = cg * 8;
  float wreg[9][8], breg[8];
#pragma unroll
  for (int j = 0; j < 8; j++) {
    breg[j] = bias[c0 + j];
#pragma unroll
    for (int kk = 0; kk < 9; kk++) wreg[kk][j] = w[(c0 + j) * 9 + kk];
  }
  for (int i = 0; i < 4; i++) {
    int token = blockIdx.x * 16 + tg * 4 + i;
    int b = token >> 10, s = token & (HW_ - 1);
    int hh = s >> 5, ww = s & 31;
    float acc[8];
#pragma unroll
    for (int j = 0; j < 8; j++) acc[j] = breg[j];
#pragma unroll
    for (int ky = 0; ky < 3; ky++) {
      int yy = hh + ky - 1;
      if (yy < 0 || yy >= HH_) continue;
#pragma unroll
      for (int kx = 0; kx < 3; kx++) {
        int xx = ww + kx - 1;
        if (xx < 0 || xx >= WW_) continue;
        ushort8 v8 = *(const ushort8*)
            &y[((size_t)(b * HW_ + yy * 32 + xx)) * C_ + c0];
        const float* wk = wreg[ky * 3 + kx];
#pragma unroll
        for (int j = 0; j < 8; j++) acc[j] += wk[j] * bf2f(v8[j]);
      }
    }
    ushort8 pk;
#pragma unroll
    for (int j = 0; j < 8; j++) pk[j] = f2bf(acc[j]);
    *(ushort8*)&out[(size_t)token * C_ + c0] = pk;
  }
}

// -------------------------------------------------------------------------
extern "C" void kernel_launch(void* const* d_in, const int* in_sizes, int n_in,
                              void* d_out, int out_size, void* d_ws,
                              size_t ws_size, hipStream_t stream) {
  const float* x = (const float*)d_in[0];
  const float* qkv_w = (const float*)d_in[1];
  const float* proj_w = (const float*)d_in[2];
  const float* proj_b = (const float*)d_in[3];
  const float* temperature = (const float*)d_in[4];
  const float* ln_g = (const float*)d_in[5];
  const float* ln_b = (const float*)d_in[6];
  const float* pos = (const float*)d_in[7];
  const float* dw_w = (const float*)d_in[8];
  const float* dw_b = (const float*)d_in[9];
  const float* pw_w = (const float*)d_in[10];
  const float* pw_b = (const float*)d_in[11];
  float* out = (float*)d_out;

  float* ws = (float*)d_ws;
  // [0,24MB)    qkv_bf (bf16; V third unwritten)
  // [24,32MB)   t_bf -> attn_out_bf -> dw_out_bf (bf16)
  // [32,40MB)   proj_bf (bf16)
  // [48,56MB)   xT bf16 -> y_bf (ln in place)
  // [56,~58.6)  weights bf16
  // [60MB,..)   qsum/ksum (8192 floats)
  // [64,72MB)   vt (V transposed, bf16)
  ushort* qkv_bf = (ushort*)ws;
  ushort* t_bf = (ushort*)(ws + (size_t)6 * 1024 * 1024);
  ushort* proj_bf = (ushort*)(ws + (size_t)8 * 1024 * 1024);
  ushort* xT_bf = (ushort*)(ws + (size_t)12 * 1024 * 1024);
  ushort* wts = (ushort*)(ws + (size_t)14 * 1024 * 1024);
  ushort* qkvw_bf = wts;
  ushort* projw_bf = wts + 786432;
  ushort* pww_bf = wts + 1048576;
  float* sums = ws + (size_t)15 * 1024 * 1024;  // qsum[4096] | ksum[4096]
  float* qsum = sums;
  float* ksum = sums + 4096;
  ushort* vtb = (ushort*)(ws + (size_t)16 * 1024 * 1024);

  const int M = BB_ * HW_;  // 8192 tokens

  // 1) prep: weights->bf16, t/xT transpose, zero sums
  prep_kernel<<<6176, 256, 0, stream>>>(x, pos, qkv_w, proj_w, pw_w, t_bf,
                                        xT_bf, wts, sums);
  // 2) qkv GEMM: q/k bf16 + norm-sums; V -> vt transposed
  gemm_qkv<<<dim3(C3_ / 128, M / 128), 256, 0, stream>>>(
      t_bf, qkvw_bf, qkv_bf, vtb, qsum, ksum);
  // 3) flash attention -> attn_out (bf16, reuses t region)
  attn_mfma_kernel<<<BB_ * NH_ * (HW_ / 64), 256, 0, stream>>>(
      qkv_bf, vtb, qsum, ksum, temperature, t_bf);
  // 4) proj GEMM (+bias, bf16 out)
  gemm_n64<1><<<dim3(C_ / 64, M / 128), 256, 0, stream>>>(
      t_bf, projw_bf, proj_b, proj_bf, nullptr, C_, C_);
  // 5) LayerNorm + residual(xT) -> y_bf (in place over xT)
  ln_residual_kernel<<<M, 256, 0, stream>>>(proj_bf, xT_bf, ln_g, ln_b,
                                            xT_bf);
  // 6) depthwise 3x3 on bf16 y -> dw_out (bf16, reuses t region)
  dwconv_kernel<<<M / 16, 256, 0, stream>>>(xT_bf, dw_w, dw_b, t_bf);
  // 7) pointwise GEMM + pw_b + residual(y_bf), NCHW -> out
  gemm_n64<2><<<dim3(C_ / 64, M / 128), 256, 0, stream>>>(
      t_bf, pww_bf, pw_b, out, xT_bf, C_, C_);
}

// Round 8
// 210.583 us; speedup vs baseline: 1.0483x; 1.0152x over previous
//
#include <hip/hip_runtime.h>
#include <math.h>

// Problem constants
#define BB_ 8
#define C_ 512
#define C3_ 1536
#define HW_ 1024
#define NH_ 8
#define DH_ 64
#define HH_ 32
#define WW_ 32

typedef __attribute__((ext_vector_type(8))) short short8;
typedef __attribute__((ext_vector_type(4))) short short4v;
typedef __attribute__((ext_vector_type(8))) unsigned short ushort8;
typedef __attribute__((ext_vector_type(4))) unsigned short ushort4_t;
typedef __attribute__((ext_vector_type(4))) float f32x4;
typedef unsigned short ushort;

__device__ inline ushort f2bf(float f) {
  union { float f; unsigned u; } v;
  v.f = f;
  unsigned r = v.u + 0x7fffu + ((v.u >> 16) & 1u);
  return (ushort)(r >> 16);
}
__device__ inline float bf2f(ushort u) {
  union { unsigned u; float f; } v;
  v.u = ((unsigned)u) << 16;
  return v.f;
}

#define GLD16(gptr, lptr)                                                     \
  __builtin_amdgcn_global_load_lds(                                           \
      (const __attribute__((address_space(1))) unsigned int*)(gptr),          \
      (__attribute__((address_space(3))) unsigned int*)(lptr), 16, 0, 0)

// PV micro-op: D += Vt_frag(4 keys) x P_frag(4 keys), 16x16 output.
__device__ inline f32x4 pv_mfma(const ushort* vp, short4v pf, f32x4 acc) {
#if __has_builtin(__builtin_amdgcn_mfma_f32_16x16x16_bf16)
  short4v vf = *(const short4v*)vp;
  return __builtin_amdgcn_mfma_f32_16x16x16_bf16(vf, pf, acc, 0, 0, 0);
#elif __has_builtin(__builtin_amdgcn_mfma_f32_16x16x16bf16_1k)
  short4v vf = *(const short4v*)vp;
  return __builtin_amdgcn_mfma_f32_16x16x16bf16_1k(vf, pf, acc, 0, 0, 0);
#else
  short4v v4 = *(const short4v*)vp;
  short8 vf = {v4[0], v4[1], v4[2], v4[3], 0, 0, 0, 0};
  short8 pf8 = {pf[0], pf[1], pf[2], pf[3], 0, 0, 0, 0};
  return __builtin_amdgcn_mfma_f32_16x16x32_bf16(vf, pf8, acc, 0, 0, 0);
#endif
}

// -------------------------------------------------------------------------
// K1 (prep): fused weight-cvt + x transpose(+pos) + qsum/ksum zeroing.
__global__ __launch_bounds__(256) void prep_kernel(
    const float* __restrict__ x, const float* __restrict__ pos,
    const float* __restrict__ qkv_w, const float* __restrict__ proj_w,
    const float* __restrict__ pw_w, ushort* __restrict__ t,
    ushort* __restrict__ xT, ushort* __restrict__ wts,
    float* __restrict__ sums) {
  const int bid = blockIdx.x;
  const int tid = threadIdx.x;
  if (bid >= 6144) {
    sums[(bid - 6144) * 256 + tid] = 0.f;
    return;
  }
  if (bid >= 1024) {
    int i = (bid - 1024) * 256 + tid;
    if (i < 786432) wts[i] = f2bf(qkv_w[i]);
    else if (i < 1048576) wts[i] = f2bf(proj_w[i - 786432]);
    else wts[i] = f2bf(pw_w[i - 1048576]);
    return;
  }
  __shared__ float tile[64][65];
  const int n0 = (bid & 15) * 64, c0 = ((bid >> 4) & 7) * 64, b = bid >> 7;
#pragma unroll
  for (int it = 0; it < 4; it++) {
    int c_l = (tid >> 4) + it * 16;
    int n_l4 = (tid & 15) * 4;
    float4 v = *(const float4*)&x[((size_t)(b * C_ + c0 + c_l)) * HW_ + n0 + n_l4];
    tile[c_l][n_l4 + 0] = v.x;
    tile[c_l][n_l4 + 1] = v.y;
    tile[c_l][n_l4 + 2] = v.z;
    tile[c_l][n_l4 + 3] = v.w;
  }
  __syncthreads();
#pragma unroll
  for (int it = 0; it < 4; it++) {
    int n_l = (tid >> 4) + it * 16;
    int c_l4 = (tid & 15) * 4;
    size_t token = (size_t)(b * HW_ + n0 + n_l);
    float4 pv = *(const float4*)&pos[(n0 + n_l) * C_ + c0 + c_l4];
    float xv0 = tile[c_l4 + 0][n_l], xv1 = tile[c_l4 + 1][n_l];
    float xv2 = tile[c_l4 + 2][n_l], xv3 = tile[c_l4 + 3][n_l];
    ushort4_t tb = {f2bf(xv0 + pv.x), f2bf(xv1 + pv.y), f2bf(xv2 + pv.z),
                    f2bf(xv3 + pv.w)};
    ushort4_t xb = {f2bf(xv0), f2bf(xv1), f2bf(xv2), f2bf(xv3)};
    *(ushort4_t*)&t[token * C_ + c0 + c_l4] = tb;
    *(ushort4_t*)&xT[token * C_ + c0 + c_l4] = xb;
  }
}

// -------------------------------------------------------------------------
// K2: qkv GEMM (m97 structure, 128x128). Epilogue: q/k bf16 + norm-sums;
// V -> transposed bf16 store into vt[bh*64+d][n].
__global__ __launch_bounds__(256) void gemm_qkv(
    const ushort* __restrict__ A, const ushort* __restrict__ Wm,
    ushort* __restrict__ out, ushort* __restrict__ vt,
    float* __restrict__ qsum, float* __restrict__ ksum) {
  const int N = C3_, K = C_;
  __shared__ alignas(16) ushort As[128 * 32];
  __shared__ alignas(16) ushort Bs[128 * 32];
  const int bn = blockIdx.x * 128, bm = blockIdx.y * 128;
  const int tid = threadIdx.x;
  const int w = tid >> 6, lane = tid & 63;
  const int wm = 64 * (w & 1), wn = 64 * (w >> 1);
  const int l15 = lane & 15, lq = lane >> 4;

  f32x4 acc[4][4];
#pragma unroll
  for (int i = 0; i < 4; i++)
#pragma unroll
    for (int j = 0; j < 4; j++) acc[i][j] = (f32x4){0.f, 0.f, 0.f, 0.f};

  const int srr = lane >> 2, sq1 = lane & 3;

  for (int k0 = 0; k0 < K; k0 += 32) {
    __syncthreads();
#pragma unroll
    for (int j = 0; j < 2; j++) {
      int r = 32 * w + 16 * j + srr;
      int q = (sq1 - (r >> 1)) & 3;
      GLD16(A + (size_t)(bm + r) * K + k0 + q * 8, &As[(32 * w + 16 * j) * 32]);
      GLD16(Wm + (size_t)(bn + r) * K + k0 + q * 8, &Bs[(32 * w + 16 * j) * 32]);
    }
    __syncthreads();
    short8 af[4], bf[4];
#pragma unroll
    for (int nt = 0; nt < 4; nt++) {
      int r = wm + nt * 16 + l15;
      af[nt] = *(const short8*)&As[r * 32 + (((lq + (r >> 1)) & 3) * 8)];
      int c = wn + nt * 16 + l15;
      bf[nt] = *(const short8*)&Bs[c * 32 + (((lq + (c >> 1)) & 3) * 8)];
    }
#pragma unroll
    for (int i = 0; i < 4; i++)
#pragma unroll
      for (int j = 0; j < 4; j++)
        acc[i][j] = __builtin_amdgcn_mfma_f32_16x16x32_bf16(af[i], bf[j],
                                                            acc[i][j], 0, 0, 0);
  }

  const int b = bm >> 10;
  if (bn < 1024) {
#pragma unroll
    for (int j = 0; j < 4; j++) {
      int c = bn + wn + j * 16 + l15;
      float ss = 0.f;
#pragma unroll
      for (int i = 0; i < 4; i++) {
#pragma unroll
        for (int r = 0; r < 4; r++) {
          int m = bm + wm + i * 16 + lq * 4 + r;
          float v = acc[i][j][r];
          ss += v * v;
          out[(size_t)m * N + c] = f2bf(v);
        }
      }
      ss += __shfl_xor(ss, 16);
      ss += __shfl_xor(ss, 32);
      if (lq == 0) {
        if (c < 512) atomicAdd(&qsum[b * 512 + c], ss);
        else atomicAdd(&ksum[b * 512 + c - 512], ss);
      }
    }
  } else {
#pragma unroll
    for (int j = 0; j < 4; j++) {
      int c = bn + wn + j * 16 + l15;
      int hd = c - 1024;
      ushort* vrow = vt + ((size_t)(b * 512 + hd)) * HW_;
#pragma unroll
      for (int i = 0; i < 4; i++) {
        int n0 = (bm & 1023) + wm + i * 16 + lq * 4;
        ushort4_t pv = {f2bf(acc[i][j][0]), f2bf(acc[i][j][1]),
                        f2bf(acc[i][j][2]), f2bf(acc[i][j][3])};
        *(ushort4_t*)&vrow[n0] = pv;
      }
    }
  }
}

// -------------------------------------------------------------------------
// bf16 MFMA GEMM 128x64 tiles. EPI 1: bf16 +bias token-major.
// EPI 2: f32 +bias +resid(bf16), NCHW store.
template <int EPI>
__global__ __launch_bounds__(256) void gemm_n64(
    const ushort* __restrict__ A, const ushort* __restrict__ Wm,
    const float* __restrict__ bias, void* __restrict__ outv,
    const ushort* __restrict__ resid, int N, int K) {
  __shared__ alignas(16) ushort As[128 * 32];
  __shared__ alignas(16) ushort Bs[64 * 32];
  const int bn = blockIdx.x * 64, bm = blockIdx.y * 128;
  const int tid = threadIdx.x;
  const int w = tid >> 6, lane = tid & 63;
  const int wm = 64 * (w & 1), wn = 32 * (w >> 1);
  const int l15 = lane & 15, lq = lane >> 4;

  f32x4 acc[4][2];
#pragma unroll
  for (int i = 0; i < 4; i++)
#pragma unroll
    for (int j = 0; j < 2; j++) acc[i][j] = (f32x4){0.f, 0.f, 0.f, 0.f};

  const int srr = lane >> 2, sq1 = lane & 3;

  for (int k0 = 0; k0 < K; k0 += 32) {
    __syncthreads();
#pragma unroll
    for (int j = 0; j < 2; j++) {
      int r = 32 * w + 16 * j + srr;
      int q = (sq1 - (r >> 1)) & 3;
      GLD16(A + (size_t)(bm + r) * K + k0 + q * 8, &As[(32 * w + 16 * j) * 32]);
    }
    {
      int r = 16 * w + srr;
      int q = (sq1 - (r >> 1)) & 3;
      GLD16(Wm + (size_t)(bn + r) * K + k0 + q * 8, &Bs[(16 * w) * 32]);
    }
    __syncthreads();
    short8 af[4], bf[2];
#pragma unroll
    for (int nt = 0; nt < 4; nt++) {
      int r = wm + nt * 16 + l15;
      af[nt] = *(const short8*)&As[r * 32 + (((lq + (r >> 1)) & 3) * 8)];
    }
#pragma unroll
    for (int j = 0; j < 2; j++) {
      int c = wn + j * 16 + l15;
      bf[j] = *(const short8*)&Bs[c * 32 + (((lq + (c >> 1)) & 3) * 8)];
    }
#pragma unroll
    for (int i = 0; i < 4; i++)
#pragma unroll
      for (int j = 0; j < 2; j++)
        acc[i][j] = __builtin_amdgcn_mfma_f32_16x16x32_bf16(af[i], bf[j],
                                                            acc[i][j], 0, 0, 0);
  }

#pragma unroll
  for (int i = 0; i < 4; i++) {
#pragma unroll
    for (int j = 0; j < 2; j++) {
      int c = bn + wn + j * 16 + l15;
      float bv = bias[c];
#pragma unroll
      for (int r = 0; r < 4; r++) {
        int m = bm + wm + i * 16 + lq * 4 + r;
        float v = acc[i][j][r] + bv;
        if (EPI == 1) {
          ((ushort*)outv)[(size_t)m * N + c] = f2bf(v);
        } else {
          int b = m >> 10, s = m & (HW_ - 1);
          ((float*)outv)[((size_t)(b * C_ + c)) * HW_ + s] =
              v + bf2f(resid[(size_t)m * C_ + c]);
        }
      }
    }
  }
}

// -------------------------------------------------------------------------
// K3: MFMA flash attention with double-buffered direct-to-LDS staging:
// one barrier per K-tile; GLD for tile kt+1 overlaps compute of tile kt.
__global__ __launch_bounds__(256) void attn_mfma_kernel(
    const ushort* __restrict__ qkv, const ushort* __restrict__ vt,
    const float* __restrict__ qsum, const float* __restrict__ ksum,
    const float* __restrict__ temp, ushort* __restrict__ o) {
  __shared__ alignas(16) ushort Ks[2][64 * 64];   // [key][d], chunk-swizzled
  __shared__ alignas(16) ushort Vts[2][64 * 64];  // [d][key], chunk-swizzled
  __shared__ float sc_lds[64];

  const int tid = threadIdx.x;
  const int w = tid >> 6, lane = tid & 63;
  const int quad = lane >> 4, lcol = lane & 15;
  const int bh = blockIdx.x >> 4;
  const int qt = blockIdx.x & 15;
  const int b = bh >> 3, h = bh & 7;
  const int q0 = qt * 64;

  if (tid < 64) {
    float qs = qsum[b * 512 + h * 64 + tid];
    float ks = ksum[b * 512 + h * 64 + tid];
    float iq = 1.0f / fmaxf(sqrtf(qs), 1e-12f);
    float ik = 1.0f / fmaxf(sqrtf(ks), 1e-12f);
    sc_lds[tid] = iq * ik * temp[h];
  }

  const ushort* kg = qkv + (size_t)b * HW_ * C3_ + C_ + h * 64;
  const ushort* vg = vt + (size_t)(bh * 64) * HW_;

  // staging: 256 threads x 2 iters cover 64 rows x 8 chunks (of 8 bf16)
  const int srow0 = tid >> 3;  // 0..31
  const int sc = tid & 7;

  // prologue: stage tile 0 into buffer 0
#pragma unroll
  for (int it = 0; it < 2; it++) {
    int row = srow0 + it * 32;
    int scg = sc ^ (row & 7);
    GLD16(kg + (size_t)row * C3_ + scg * 8, &Ks[0][w * 512 + it * 2048]);
    GLD16(vg + (size_t)row * HW_ + scg * 8, &Vts[0][w * 512 + it * 2048]);
  }
  __syncthreads();

  // Q fragment (B-operand of S^T = K·Q^T), scales folded in.
  short8 qf[2];
  {
    const int m = q0 + w * 16 + lcol;
    const ushort* qrow = qkv + ((size_t)(b * HW_ + m)) * C3_ + h * 64;
#pragma unroll
    for (int kc = 0; kc < 2; kc++) {
      union { short8 v; ushort u[8]; } pk;
#pragma unroll
      for (int j = 0; j < 8; j++) {
        int d = kc * 32 + quad * 8 + j;
        pk.u[j] = f2bf(bf2f(qrow[d]) * sc_lds[d]);
      }
      qf[kc] = pk.v;
    }
  }

  f32x4 ot[4];
#pragma unroll
  for (int dt = 0; dt < 4; dt++) ot[dt] = (f32x4){0.f, 0.f, 0.f, 0.f};
  float lsum = 0.f;

  for (int kt = 0; kt < 16; kt++) {
    if (kt > 0) __syncthreads();  // drains GLD(kt) + prior buffer reads
    const int cur = kt & 1;
    if (kt + 1 < 16) {
      const int nxt = cur ^ 1;
#pragma unroll
      for (int it = 0; it < 2; it++) {
        int row = srow0 + it * 32;
        int scg = sc ^ (row & 7);
        GLD16(kg + (size_t)((kt + 1) * 64 + row) * C3_ + scg * 8,
              &Ks[nxt][w * 512 + it * 2048]);
        GLD16(vg + (size_t)row * HW_ + (kt + 1) * 64 + scg * 8,
              &Vts[nxt][w * 512 + it * 2048]);
      }
    }

    // S^T = K·Q^T
    f32x4 sfr[4];
#pragma unroll
    for (int nt = 0; nt < 4; nt++) sfr[nt] = (f32x4){0.f, 0.f, 0.f, 0.f};
#pragma unroll
    for (int kc = 0; kc < 2; kc++) {
#pragma unroll
      for (int nt = 0; nt < 4; nt++) {
        int row = nt * 16 + lcol;
        short8 kf = *(const short8*)
            &Ks[cur][row * 64 + (((kc * 4 + quad) ^ (row & 7)) * 8)];
        sfr[nt] =
            __builtin_amdgcn_mfma_f32_16x16x32_bf16(kf, qf[kc], sfr[nt], 0, 0, 0);
      }
    }

    // exp (fixed max: scores bounded ~0.07) + per-lane sum + pack P
    ushort pk[4][4];
#pragma unroll
    for (int nt = 0; nt < 4; nt++) {
#pragma unroll
      for (int r = 0; r < 4; r++) {
        float e = __expf(sfr[nt][r]);
        lsum += e;
        pk[nt][r] = f2bf(e);
      }
    }

    // O^T += V^T · P^T  (x16 MFMAs, P from registers)
#pragma unroll
    for (int nt = 0; nt < 4; nt++) {
      short4v pf = {(short)pk[nt][0], (short)pk[nt][1], (short)pk[nt][2],
                    (short)pk[nt][3]};
      int key = nt * 16 + quad * 4;
#pragma unroll
      for (int dt = 0; dt < 4; dt++) {
        int d = dt * 16 + lcol;
        const ushort* vp =
            &Vts[cur][d * 64 + (((key >> 3) ^ (d & 7)) * 8) + (key & 7)];
        ot[dt] = pv_mfma(vp, pf, ot[dt]);
      }
    }
  }

  lsum += __shfl_xor(lsum, 16);
  lsum += __shfl_xor(lsum, 32);
  const float inv = 1.0f / lsum;

  const int m = q0 + w * 16 + lcol;
  ushort* orow = o + ((size_t)(b * HW_ + m)) * C_ + h * 64;
#pragma unroll
  for (int dt = 0; dt < 4; dt++) {
    ushort4_t pkb = {f2bf(ot[dt][0] * inv), f2bf(ot[dt][1] * inv),
                     f2bf(ot[dt][2] * inv), f2bf(ot[dt][3] * inv)};
    *(ushort4_t*)&orow[dt * 16 + quad * 4] = pkb;
  }
}

// -------------------------------------------------------------------------
// K5: LayerNorm, wave-per-token (no LDS, no barriers). bf16 in/out,
// residual xT bf16; writes y_bf in place over xT.
__global__ __launch_bounds__(256) void ln_residual_kernel(
    const ushort* __restrict__ po, const ushort* xT,
    const float* __restrict__ g, const float* __restrict__ bb, ushort* ybf) {
  const int wv = threadIdx.x >> 6, lane = threadIdx.x & 63;
  const int token = blockIdx.x * 4 + wv;
  const int c0 = lane * 8;
  ushort8 p8 = *(const ushort8*)&po[(size_t)token * C_ + c0];
  float v[8];
  float s = 0.f;
#pragma unroll
  for (int j = 0; j < 8; j++) {
    v[j] = bf2f(p8[j]);
    s += v[j];
  }
#pragma unroll
  for (int off = 32; off; off >>= 1) s += __shfl_xor(s, off);
  float mu = s * (1.0f / C_);
  float vs = 0.f;
#pragma unroll
  for (int j = 0; j < 8; j++) {
    v[j] -= mu;
    vs += v[j] * v[j];
  }
#pragma unroll
  for (int off = 32; off; off >>= 1) vs += __shfl_xor(vs, off);
  float rstd = rsqrtf(vs * (1.0f / C_) + 1e-5f);
  float4 g0 = *(const float4*)&g[c0], g1 = *(const float4*)&g[c0 + 4];
  float4 b0 = *(const float4*)&bb[c0], b1 = *(const float4*)&bb[c0 + 4];
  ushort8 r8 = *(const ushort8*)&xT[(size_t)token * C_ + c0];
  float gg[8] = {g0.x, g0.y, g0.z, g0.w, g1.x, g1.y, g1.z, g1.w};
  float bbv[8] = {b0.x, b0.y, b0.z, b0.w, b1.x, b1.y, b1.z, b1.w};
  ushort8 pk;
#pragma unroll
  for (int j = 0; j < 8; j++)
    pk[j] = f2bf(v[j] * rstd * gg[j] + bbv[j] + bf2f(r8[j]));
  *(ushort8*)&ybf[(size_t)token * C_ + c0] = pk;
}

// -------------------------------------------------------------------------
// K6: depthwise 3x3 SAME on bf16 y (token-major) -> bf16 out (+dw bias)
__global__ __launch_bounds__(256) void dwconv_kernel(
    const ushort* __restrict__ y, const float* __restrict__ w,
    const float* __restrict__ bias, ushort* __restrict__ out) {
  const int cg = threadIdx.x & 63, tg = threadIdx.x >> 6;
  const int c0 = cg * 8;
  float wreg[9][8], breg[8];
#pragma unroll
  for (int j = 0; j < 8; j++) {
    breg[j] = bias[c0 + j];
#pragma unroll
    for (int kk = 0; kk < 9; kk++) wreg[kk][j] = w[(c0 + j) * 9 + kk];
  }
  for (int i = 0; i < 4; i++) {
    int token = blockIdx.x * 16 + tg * 4 + i;
    int b = token >> 10, s = token & (HW_ - 1);
    int hh = s >> 5, ww = s & 31;
    float acc[8];
#pragma unroll
    for (int j = 0; j < 8; j++) acc[j] = breg[j];
#pragma unroll
    for (int ky = 0; ky < 3; ky++) {
      int yy = hh + ky - 1;
      if (yy < 0 || yy >= HH_) continue;
#pragma unroll
      for (int kx = 0; kx < 3; kx++) {
        int xx = ww + kx - 1;
        if (xx < 0 || xx >= WW_) continue;
        ushort8 v8 = *(const ushort8*)
            &y[((size_t)(b * HW_ + yy * 32 + xx)) * C_ + c0];
        const float* wk = wreg[ky * 3 + kx];
#pragma unroll
        for (int j = 0; j < 8; j++) acc[j] += wk[j] * bf2f(v8[j]);
      }
    }
    ushort8 pk;
#pragma unroll
    for (int j = 0; j < 8; j++) pk[j] = f2bf(acc[j]);
    *(ushort8*)&out[(size_t)token * C_ + c0] = pk;
  }
}

// -------------------------------------------------------------------------
extern "C" void kernel_launch(void* const* d_in, const int* in_sizes, int n_in,
                              void* d_out, int out_size, void* d_ws,
                              size_t ws_size, hipStream_t stream) {
  const float* x = (const float*)d_in[0];
  const float* qkv_w = (const float*)d_in[1];
  const float* proj_w = (const float*)d_in[2];
  const float* proj_b = (const float*)d_in[3];
  const float* temperature = (const float*)d_in[4];
  const float* ln_g = (const float*)d_in[5];
  const float* ln_b = (const float*)d_in[6];
  const float* pos = (const float*)d_in[7];
  const float* dw_w = (const float*)d_in[8];
  const float* dw_b = (const float*)d_in[9];
  const float* pw_w = (const float*)d_in[10];
  const float* pw_b = (const float*)d_in[11];
  float* out = (float*)d_out;

  float* ws = (float*)d_ws;
  ushort* qkv_bf = (ushort*)ws;
  ushort* t_bf = (ushort*)(ws + (size_t)6 * 1024 * 1024);
  ushort* proj_bf = (ushort*)(ws + (size_t)8 * 1024 * 1024);
  ushort* xT_bf = (ushort*)(ws + (size_t)12 * 1024 * 1024);
  ushort* wts = (ushort*)(ws + (size_t)14 * 1024 * 1024);
  ushort* qkvw_bf = wts;
  ushort* projw_bf = wts + 786432;
  ushort* pww_bf = wts + 1048576;
  float* sums = ws + (size_t)15 * 1024 * 1024;
  float* qsum = sums;
  float* ksum = sums + 4096;
  ushort* vtb = (ushort*)(ws + (size_t)16 * 1024 * 1024);

  const int M = BB_ * HW_;  // 8192 tokens

  // 1) prep: weights->bf16, t/xT transpose, zero sums
  prep_kernel<<<6176, 256, 0, stream>>>(x, pos, qkv_w, proj_w, pw_w, t_bf,
                                        xT_bf, wts, sums);
  // 2) qkv GEMM: q/k bf16 + norm-sums; V -> vt transposed
  gemm_qkv<<<dim3(C3_ / 128, M / 128), 256, 0, stream>>>(
      t_bf, qkvw_bf, qkv_bf, vtb, qsum, ksum);
  // 3) flash attention -> attn_out (bf16, reuses t region)
  attn_mfma_kernel<<<BB_ * NH_ * (HW_ / 64), 256, 0, stream>>>(
      qkv_bf, vtb, qsum, ksum, temperature, t_bf);
  // 4) proj GEMM (+bias, bf16 out)
  gemm_n64<1><<<dim3(C_ / 64, M / 128), 256, 0, stream>>>(
      t_bf, projw_bf, proj_b, proj_bf, nullptr, C_, C_);
  // 5) LayerNorm + residual(xT) -> y_bf (in place over xT), wave-per-token
  ln_residual_kernel<<<M / 4, 256, 0, stream>>>(proj_bf, xT_bf, ln_g, ln_b,
                                                xT_bf);
  // 6) depthwise 3x3 on bf16 y -> dw_out (bf16, reuses t region)
  dwconv_kernel<<<M / 16, 256, 0, stream>>>(xT_bf, dw_w, dw_b, t_bf);
  // 7) pointwise GEMM + pw_b + residual(y_bf), NCHW -> out
  gemm_n64<2><<<dim3(C_ / 64, M / 128), 256, 0, stream>>>(
      t_bf, pww_bf, pw_b, out, xT_bf, C_, C_);
}